// Round 10
// baseline (384.792 us; speedup 1.0000x reference)
//
#include <hip/hip_runtime.h>

// EdgeConv: B=32, N=2048, D=16, PCD=2, K_NN=16, FILTERS=64
// out[b,n,0:64]  = max(y_n, max_k y_{nn_k} - y_n) + b   where y = x@W (linearity)
// out[b,n,64:80] = x[b,n,:]
//
// R20 = R19 with ONE line fixed: the SCAN db edge mask.
//   R18/R19 failed bit-identically (2.734375) across two different ownership
//   mechanisms -> bug in shared code. Root cause: R18 changed R17's correct
//   db mask (p+1 >= HIV) to (pc+1 >= HIV). Tail iteration p=2048, HIV=2048:
//   pc=2046, pc+1=2047 < HIV -> rank 2047 (max-x point; rank deterministic
//   in any bucket order -> identical failures) inserted TWICE -> 16th order
//   statistic shifted down -> Tub under-estimated -> missed true neighbors
//   for queries whose extent ends at 2048. Proof of fixed mask: quarters
//   disjoint; p<=N_-2: ranks p,p+1 eval iff < HIV; p>N_-2 => p even => p>=2048
//   >= HIV => both masked. No duplicates, no holes.
//   R19 structure kept: deterministic counting sort (sorted position = stable
//   rank; permutation identical in all 32 blocks of a batch), stage-1 window
//   SCAN -> T0 -> x-extent -> stage-2 SCAN -> Tub -> verbatim f32 screen ->
//   exact T + {d<T} + orig-index-ascending ties. Per-candidate numerics
//   R11/R16-bit-exact; max-pool order-invariant => output set-identical.

#define B_  32
#define N_  2048
#define D_  16
#define F_  64
#define K_  16
#define OUTD (F_ + D_)   // 80
#define NQ  64           // queries per block (sorted ranks)
#define NS  4            // waves = extent quarters
#define CAP 24           // survivor cap per (query, wave)
#define NB  64           // x-buckets

typedef _Float16 h2 __attribute__((ext_vector_type(2)));

static __device__ __forceinline__ h2 h2min(h2 a, h2 b) { return __builtin_elementwise_min(a, b); }
static __device__ __forceinline__ h2 h2max(h2 a, h2 b) { return __builtin_elementwise_max(a, b); }
static __device__ __forceinline__ _Float16 hmn(_Float16 a, _Float16 b) { return __builtin_elementwise_min(a, b); }
static __device__ __forceinline__ _Float16 hmx(_Float16 a, _Float16 b) { return __builtin_elementwise_max(a, b); }
static __device__ __forceinline__ unsigned short h2b(_Float16 h) { return __builtin_bit_cast(unsigned short, h); }
static __device__ __forceinline__ _Float16 b2h(unsigned short b) { return __builtin_bit_cast(_Float16, b); }

// insert ordered pair y0<=y1 into ascending sorted-16 (drop 2 largest) — exact
static __device__ __forceinline__ void pair_ins(_Float16 (&k)[16], _Float16 y0, _Float16 y1) {
#pragma unroll
    for (int j = 15; j >= 2; --j)
        k[j] = hmn(hmn(k[j], hmx(k[j - 1], y0)), hmx(k[j - 2], y1));
    k[1] = hmn(hmn(k[1], hmx(k[0], y0)), y1);
    k[0] = hmn(k[0], y0);
}

static __device__ __forceinline__ int xbucket(float xv) {
    return (int)fminf(fmaxf((xv + 5.0f) * 6.4f, 0.0f), 63.0f);  // monotone, clamped
}

// ---------------- K1: Y = X * W  (bias folded into fused kernel) ------------
__global__ __launch_bounds__(256) void proj_kernel(const float* __restrict__ x,
                                                   const float* __restrict__ W,
                                                   float* __restrict__ Y) {
    __shared__ float Ws[D_ * F_];     // 4 KB
    __shared__ float xs[16][D_];      // 1 KB
    const int t = threadIdx.x;
    for (int i = t; i < D_ * F_; i += 256) Ws[i] = W[i];
    const int p0 = blockIdx.x * 16;
    ((float*)xs)[t] = x[(size_t)p0 * D_ + t];   // coalesced 1 KB
    __syncthreads();
    const int w = t >> 6, f = t & 63;
#pragma unroll
    for (int i = 0; i < 4; i++) {
        const int pw = w * 4 + i;
        float acc = 0.f;
#pragma unroll
        for (int d = 0; d < D_; d++) acc = fmaf(xs[pw][d], Ws[d * F_ + f], acc);
        Y[(size_t)(p0 + pw) * F_ + f] = acc;
    }
}

// ---------------- K2: exact 16-NN + fused conv-max-pool epilogue ------------
__global__ __launch_bounds__(256, 3) void knn_kernel(const float* __restrict__ x,
                                                     const float* __restrict__ bias,
                                                     const float* __restrict__ Y,
                                                     float* __restrict__ out) {
    __shared__ float2 sxy[N_];                       // 16384 B (x-sorted, DETERMINISTIC)
    __shared__ float  ssq[N_];                       // 8192 B
    __shared__ unsigned short sidx[N_];              // 4096 B (orig index)
    // overlay: tab (count table) -> arr32 (merge) -> survb (pass2/finish)
    __shared__ __align__(16) char region[16384];     // 16384 B
    __shared__ unsigned int   bstart[NB + 1];        // 260 B (deterministic)
    __shared__ unsigned int   bcnt[NB];              // 256 B
    __shared__ float TubA[NQ];                       // 256 B
    __shared__ unsigned short idxL[NQ][18];          // 2304 B (orig indices)
    __shared__ unsigned short scnt[NS][NQ];          // 512 B   => ~48.6 KB

    unsigned char (*tab)[NB] = (unsigned char (*)[NB])region;                 // [256][64]
    unsigned (*arr32)[NQ][9] = (unsigned (*)[NQ][9])region;                   // 6912 B
    unsigned short (*survb)[NQ][CAP] = (unsigned short (*)[NQ][CAP])region;   // 12288 B

    const int b = blockIdx.x >> 5;                 // 32 blocks per batch
    const int qbase = (blockIdx.x & 31) * NQ;      // sorted-rank base
    const int t = threadIdx.x;
    const int s = t >> 6;                          // wave id
    const int qi = t & 63;                         // lane

    // ---- load my 8 points (m = 8t..8t+7) into registers; bucket them ----
    const float* xb = x + (size_t)b * N_ * D_;
    float2 p8[8];
    int bk8[8];
#pragma unroll
    for (int j = 0; j < 8; ++j) {
        const int m = t * 8 + j;
        p8[j] = make_float2(xb[m * D_ + 0], xb[m * D_ + 1]);   // R11-style scalar loads
        bk8[j] = xbucket(p8[j].x);
    }
    for (int i = t; i < 4096; i += 256) ((unsigned*)region)[i] = 0u;  // zero tab
    __syncthreads();                               // B1

    // ---- per-thread-row bucket counts (row t private -> race-free) ----
#pragma unroll
    for (int j = 0; j < 8; ++j) tab[t][bk8[j]]++;
    __syncthreads();                               // B2

    // ---- column prefix over threads (wave 0, lane = bucket), m-order ----
    if (t < NB) {
        unsigned run = 0;
        for (int i = 0; i < 256; ++i) {
            unsigned c = tab[i][t];
            tab[i][t] = (unsigned char)run;        // run < bucket count <= ~190 < 256
            run += c;
        }
        bcnt[t] = run;
    }
    __syncthreads();                               // B3

    if (t == 0) {                                  // serial bucket prefix: bulletproof
        unsigned acc = 0;
        for (int i = 0; i < NB; ++i) { bstart[i] = acc; acc += bcnt[i]; }
        bstart[NB] = acc;                          // = N_
    }
    __syncthreads();                               // B4

    // ---- deterministic scatter: sr unique, identical in every block ----
#pragma unroll
    for (int j = 0; j < 8; ++j) {
        const int bk = bk8[j];
        int loc = 0;
#pragma unroll
        for (int jj = 0; jj < 8; ++jj) if (jj < j && bk8[jj] == bk) loc++;
        const int sr = (int)bstart[bk] + (int)tab[t][bk] + loc;
        const float2 p = p8[j];
        sxy[sr] = p;
        ssq[sr] = __fadd_rn(__fmul_rn(p.x, p.x), __fmul_rn(p.y, p.y));  // verbatim bits
        sidx[sr] = (unsigned short)(t * 8 + j);
    }
    __syncthreads();                               // B5

    const int qrank = qbase + qi;                  // lane = sorted-rank query
    const float2 qp = sxy[qrank];
    const float sqn = ssq[qrank];
    const int   mq  = (int)sidx[qrank];            // orig id of my query
    const float n2x = -2.0f * qp.x, n2y = -2.0f * qp.y;   // exact

    const _Float16 hinf = b2h((unsigned short)0x7C00);
    h2 key2[16];
    _Float16 keyl[16];

// packed-f16 dual sorted-16 over [LOV,HIV) split 4 ways + merge -> TubA (R11 core)
// edge masks (PROVEN): da dead iff p!=pc or p>=HIV; db dead iff p+1>=HIV.
// p<=N_-2: ranks p,p+1 eval iff <HIV. p>N_-2 => p even => p>=2048>=HIV => both
// masked. No duplicates (R18/R19's pc+1 mask kept rank 2047 alive at p=2048).
#define SCAN(LOV, HIV)                                                          \
    {                                                                           \
        _Pragma("unroll") for (int j = 0; j < 16; ++j) key2[j] = (h2){hinf, hinf}; \
        const int Lsc = (HIV) - (LOV);                                          \
        const int Lq = (((Lsc + 3) >> 2) + 1) & ~1;                             \
        const int p0 = (LOV) + s * Lq;                                          \
        for (int i = 0; i < Lq; i += 2) {                                       \
            int p = p0 + i;                                                     \
            int pc = (p > N_ - 2) ? (N_ - 2) : p;                               \
            float2 pa = sxy[pc];     float sa = ssq[pc];                        \
            float2 pb = sxy[pc + 1]; float sb = ssq[pc + 1];                    \
            float da = __fmaf_rn(n2y, pa.y, __fmaf_rn(n2x, pa.x, sqn + sa));    \
            float db = __fmaf_rn(n2y, pb.y, __fmaf_rn(n2x, pb.x, sqn + sb));    \
            if (p != pc || p >= (HIV)) da = INFINITY;                           \
            if (p + 1 >= (HIV)) db = INFINITY;                                  \
            h2 v = __builtin_bit_cast(h2, __builtin_amdgcn_cvt_pkrtz(da, db));  \
            _Pragma("unroll") for (int j = 15; j >= 1; --j)                     \
                key2[j] = h2min(key2[j], h2max(key2[j - 1], v));                \
            key2[0] = h2min(key2[0], v);                                        \
        }                                                                       \
        _Pragma("unroll") for (int j = 0; j < 16; ++j) keyl[j] = key2[j].x;     \
        _Pragma("unroll") for (int tt = 0; tt < 8; ++tt)                        \
            pair_ins(keyl, key2[2 * tt].y, key2[2 * tt + 1].y);                 \
        if (s > 0) {                                                            \
            _Pragma("unroll") for (int tt = 0; tt < 8; ++tt)                    \
                arr32[s - 1][qi][tt] = (unsigned)h2b(keyl[2 * tt]) |            \
                                       ((unsigned)h2b(keyl[2 * tt + 1]) << 16); \
        }                                                                       \
        __syncthreads();                                                        \
        if (s == 0) {                                                           \
            for (int ss = 0; ss < NS - 1; ++ss) {                               \
                _Pragma("unroll") for (int tt = 0; tt < 8; ++tt) {              \
                    unsigned w32 = arr32[ss][qi][tt];                           \
                    pair_ins(keyl, b2h((unsigned short)(w32 & 0xffffu)),        \
                                   b2h((unsigned short)(w32 >> 16)));           \
                }                                                               \
            }                                                                   \
            float tub = (float)b2h((unsigned short)(h2b(keyl[15]) + 2));        \
            TubA[qi] = fmaxf(tub, 7e-5f);                                       \
        }                                                                       \
        __syncthreads();                                                        \
    }

    // ---- stage 1: rank window around the queries (>=144 pts) -> T0 >= T_ver
    const int winLo = (qbase - 80 > 0) ? (qbase - 80) : 0;
    const int winHi = (qbase + NQ + 80 < N_) ? (qbase + NQ + 80) : N_;
    SCAN(winLo, winHi)
    const float T0 = TubA[qi];

    // ---- extent from T0: bucket-aligned superset of {m : d_ver(m) <= T_ver}
    const float r = sqrtf(T0 * 1.005f) * 1.0001f + 1e-6f;
    float xLo = qp.x - r, xHi = qp.x + r;
    for (int off = 32; off; off >>= 1) {           // wave-reduce (same all waves)
        xLo = fminf(xLo, __shfl_xor(xLo, off));
        xHi = fmaxf(xHi, __shfl_xor(xHi, off));
    }
    int Lo2 = (int)bstart[xbucket(xLo)];
    int Hi2 = (int)bstart[xbucket(xHi) + 1];
    if (winLo < Lo2) Lo2 = winLo;                  // union with stage-1 window
    if (winHi > Hi2) Hi2 = winHi;

    // ---- stage 2: exact pass-1 over extent -> Tub (> T_ver by R11 margin)
    SCAN(Lo2, Hi2)
    const float Tub = TubA[qi];

    // ---- pass 2: VERBATIM f32 survivors d < Tub over extent (rank refs)
    {
        const int Lsc = Hi2 - Lo2;
        const int Lq = (((Lsc + 3) >> 2) + 1) & ~1;
        const int p0 = Lo2 + s * Lq;
        int sc = 0;
        for (int i = 0; i < Lq; ++i) {
            int p = p0 + i;
            if (p >= Hi2) break;                   // uniform within wave
            float2 pp = sxy[p];
            float dot = __fmaf_rn(qp.y, pp.y, __fmul_rn(qp.x, pp.x));
            float d   = __fsub_rn(__fadd_rn(sqn, ssq[p]), __fmul_rn(2.f, dot));
            if (d < Tub) { if (sc < CAP) survb[s][qi][sc] = (unsigned short)p; sc++; }
        }
        scnt[s][qi] = (unsigned short)((sc < CAP) ? sc : CAP);
    }
    __syncthreads();                               // B (arr32 dead, survb live)

    // ---- finish (wave 0): exact verbatim T; emit set {d<T} + min-orig ties
    if (s == 0) {
        float key[16];
#pragma unroll
        for (int j = 0; j < 16; ++j) key[j] = INFINITY;
        for (int ss = 0; ss < NS; ++ss) {
            int n = (int)scnt[ss][qi];
            for (int j = 0; j < n; ++j) {
                int rr = (int)survb[ss][qi][j];
                float2 pp = sxy[rr];
                float dot = __fmaf_rn(qp.y, pp.y, __fmul_rn(qp.x, pp.x));
                float d   = __fsub_rn(__fadd_rn(sqn, ssq[rr]), __fmul_rn(2.f, dot));
#pragma unroll
                for (int jj = 15; jj >= 1; --jj)
                    key[jj] = fminf(key[jj], fmaxf(key[jj - 1], d));
                key[0] = fminf(key[0], d);
            }
        }
        const float T = key[15];                   // exact global 16th smallest
        int w = 0;
        for (int ss = 0; ss < NS; ++ss) {          // {d<T}: set (pool invariant)
            int n = (int)scnt[ss][qi];
            for (int j = 0; j < n; ++j) {
                int rr = (int)survb[ss][qi][j];
                float2 pp = sxy[rr];
                float dot = __fmaf_rn(qp.y, pp.y, __fmul_rn(qp.x, pp.x));
                float d   = __fsub_rn(__fadd_rn(sqn, ssq[rr]), __fmul_rn(2.f, dot));
                if (d < T && w < K_) idxL[qi][w++] = sidx[rr];
            }
        }
        int last = -1;                             // ties: ascending ORIG index
        while (w < K_) {
            int best = 70000;
            for (int ss = 0; ss < NS; ++ss) {
                int n = (int)scnt[ss][qi];
                for (int j = 0; j < n; ++j) {
                    int rr = (int)survb[ss][qi][j];
                    float2 pp = sxy[rr];
                    float dot = __fmaf_rn(qp.y, pp.y, __fmul_rn(qp.x, pp.x));
                    float d   = __fsub_rn(__fadd_rn(sqn, ssq[rr]), __fmul_rn(2.f, dot));
                    if (d == T) {
                        int o = (int)sidx[rr];
                        if (o > last && o < best) best = o;
                    }
                }
            }
            if (best == 70000) break;              // safety
            idxL[qi][w++] = (unsigned short)best;
            last = best;
        }
        while (w < K_) idxL[qi][w++] = (unsigned short)mq;   // defensive
    }
    __syncthreads();                               // B (survb dead)

    // ---- fused pool epilogue: wave s handles queries s*16 .. s*16+15
    const int f = qi;                              // lane = filter (64)
    const float bf = bias[f];
    const float* Yb = Y + (size_t)b * N_ * F_;
    for (int i = 0; i < 16; i++) {
        const int qq = s * 16 + i;                 // block-local sorted rank
        const int go = (int)sidx[qbase + qq];      // orig point id (broadcast)
        const float yn = Yb[(size_t)go * F_ + f];
        float M = -INFINITY;
#pragma unroll
        for (int k = 0; k < K_; k++) {
            int m = (int)idxL[qq][k];              // orig neighbor id (broadcast)
            M = fmaxf(M, Yb[(size_t)m * F_ + f]);  // coalesced 256B row
        }
        const size_t pb = (size_t)b * N_ + go;
        out[pb * OUTD + f] = fmaxf(yn, M - yn) + bf;
        if (f < D_) out[pb * OUTD + F_ + f] = xb[(size_t)go * D_ + f];
    }
}

extern "C" void kernel_launch(void* const* d_in, const int* in_sizes, int n_in,
                              void* d_out, int out_size, void* d_ws, size_t ws_size,
                              hipStream_t stream) {
    const float* x    = (const float*)d_in[0];
    const float* W    = (const float*)d_in[1];
    const float* bias = (const float*)d_in[2];
    float* out = (float*)d_out;

    float* Y = (float*)d_ws;                       // 16.78 MB scratch

    proj_kernel<<<B_ * N_ / 16, 256, 0, stream>>>(x, W, Y);
    knn_kernel <<<B_ * (N_ / NQ), 256, 0, stream>>>(x, bias, Y, out);
}